// Round 1
// baseline (640.009 us; speedup 1.0000x reference)
//
#include <hip/hip_runtime.h>
#include <hip/hip_bf16.h>
#include <math.h>

// ---------------- types / helpers ----------------
typedef __attribute__((ext_vector_type(8))) short bf16x8;   // 8 bf16 in 4 VGPRs
typedef __attribute__((ext_vector_type(4))) float f32x4;
typedef __attribute__((ext_vector_type(4))) unsigned int u32x4;

#define DEV static __device__ __forceinline__

constexpr int TT   = 2048;      // sequence length
constexpr int DDIM = 2048;      // model dim
constexpr int QKVN = 3072;      // 2048 q + 512 k + 512 v
constexpr int MROWS = 4096;     // B*T
constexpr float RSCALE = 0.08838834764831845f;  // 1/sqrt(128)
constexpr float LOG2E  = 1.4426950408889634f;
constexpr float SC2    = RSCALE * LOG2E;
constexpr float REPS   = 1.1920928955078125e-07f;

DEV unsigned short f2b(float f) {            // f32 -> bf16 RNE
  union { float f; unsigned int u; } v; v.f = f;
  unsigned int u = v.u;
  return (unsigned short)((u + 0x7fffu + ((u >> 16) & 1u)) >> 16);
}
DEV float b2f(unsigned short h) {
  union { unsigned int u; float f; } v; v.u = ((unsigned int)h) << 16;
  return v.f;
}
DEV f32x4 mfma16(bf16x8 a, bf16x8 b, f32x4 c) {
  return __builtin_amdgcn_mfma_f32_16x16x32_bf16(a, b, c, 0, 0, 0);
}
DEV void gload_lds16(const void* g, void* l) {
  __builtin_amdgcn_global_load_lds(
      (const __attribute__((address_space(1))) unsigned int*)g,
      (__attribute__((address_space(3))) unsigned int*)l, 16, 0, 0);
}

// ---------------- 1. f32 -> bf16 convert ----------------
__global__ __launch_bounds__(256) void cvt_kernel(const float* __restrict__ in,
                                                  unsigned short* __restrict__ out,
                                                  int n4) {
  int i = blockIdx.x * 256 + threadIdx.x;
  if (i < n4) {
    float4 v = ((const float4*)in)[i];
    ushort4 o;
    o.x = f2b(v.x); o.y = f2b(v.y); o.z = f2b(v.z); o.w = f2b(v.w);
    ((ushort4*)out)[i] = o;
  }
}

// ---------------- 2/5. GEMM: C[M,N] = A[M,K] * B[N,K]^T (bf16 in, CT out) ---
// m97-style: 128x128 tile, BK=32, 4 waves (2x2), global_load_lds width 16.
template <typename CT>
__global__ __launch_bounds__(256) void gemm_bt(const unsigned short* __restrict__ A,
                                               const unsigned short* __restrict__ B,
                                               CT* __restrict__ C,
                                               int M, int N, int K) {
  __shared__ unsigned short As[128 * 32];
  __shared__ unsigned short Bs[128 * 32];
  const int tid = threadIdx.x;
  const int l = tid & 63, w = tid >> 6;
  const int wr = w >> 1, wc = w & 1;
  const long bm = (long)blockIdx.y * 128, bn = (long)blockIdx.x * 128;

  // staging map: pass p element = p*2048 + tid*8 -> row = e/32, col = e%32
  const int r0 = tid >> 2;
  const int c0 = (tid & 3) * 8;
  const unsigned short* Ag0 = A + (bm + r0) * (long)K + c0;
  const unsigned short* Ag1 = A + (bm + r0 + 64) * (long)K + c0;
  const unsigned short* Bg0 = B + (bn + r0) * (long)K + c0;
  const unsigned short* Bg1 = B + (bn + r0 + 64) * (long)K + c0;
  char* lA = (char*)As + w * 1024;   // wave-uniform base; HW adds lane*16
  char* lB = (char*)Bs + w * 1024;

  f32x4 acc[4][4];
#pragma unroll
  for (int m = 0; m < 4; ++m)
#pragma unroll
    for (int n = 0; n < 4; ++n) acc[m][n] = f32x4{0.f, 0.f, 0.f, 0.f};

  const int lr = l & 15;
  const int lk = (l >> 4) * 8;

  for (int k0 = 0; k0 < K; k0 += 32) {
    gload_lds16(Ag0 + k0, lA);
    gload_lds16(Ag1 + k0, lA + 4096);
    gload_lds16(Bg0 + k0, lB);
    gload_lds16(Bg1 + k0, lB + 4096);
    __syncthreads();   // vmcnt(0)+lgkm drain before barrier (compiler-emitted)
    bf16x8 af[4], bfr[4];
#pragma unroll
    for (int m = 0; m < 4; ++m)
      af[m] = *(const bf16x8*)(As + (wr * 64 + m * 16 + lr) * 32 + lk);
#pragma unroll
    for (int n = 0; n < 4; ++n)
      bfr[n] = *(const bf16x8*)(Bs + (wc * 64 + n * 16 + lr) * 32 + lk);
#pragma unroll
    for (int m = 0; m < 4; ++m)
#pragma unroll
      for (int n = 0; n < 4; ++n)
        acc[m][n] = mfma16(af[m], bfr[n], acc[m][n]);
    __syncthreads();   // protect LDS from next-iter staging
  }

#pragma unroll
  for (int m = 0; m < 4; ++m)
#pragma unroll
    for (int n = 0; n < 4; ++n)
#pragma unroll
      for (int r = 0; r < 4; ++r) {
        long row = bm + wr * 64 + m * 16 + (l >> 4) * 4 + r;
        long col = bn + wc * 64 + n * 16 + (l & 15);
        float val = acc[m][n][r];
        if constexpr (sizeof(CT) == 2)
          ((unsigned short*)C)[row * N + col] = f2b(val);
        else
          ((float*)C)[row * N + col] = val;
      }
}

// ---------------- 3. RoPE + RMSNorm (q heads 0..15, k heads 16..19) --------
__global__ __launch_bounds__(256) void rope_norm_kernel(unsigned short* __restrict__ qkv,
                                                        const float* __restrict__ qw,
                                                        const float* __restrict__ kw) {
  const int slot = blockIdx.x * 4 + (threadIdx.x >> 6);
  const int l = threadIdx.x & 63;
  const int bt = slot / 20;
  const int hs = slot - bt * 20;
  const int t = bt & (TT - 1);
  const bool isq = hs < 16;
  const int col0 = isq ? hs * 128 : 2048 + (hs - 16) * 128;
  const float* w = isq ? qw : kw;
  unsigned short* p = qkv + (long)bt * QKVN + col0;

  unsigned int pr = *(const unsigned int*)(p + 2 * l);
  float xr = b2f((unsigned short)(pr & 0xffffu));
  float xi = b2f((unsigned short)(pr >> 16));

  // inv_freq = 10000^(-l/64) = exp2(-l * log2(10000)/64)
  float ang = (float)t * exp2f(-0.207620509f * (float)l);
  float s = sinf(ang), c = cosf(ang);
  float orr = xr * c - xi * s;
  float oii = xr * s + xi * c;

  float ss = orr * orr + oii * oii;
#pragma unroll
  for (int d = 1; d < 64; d <<= 1) ss += __shfl_xor(ss, d);
  float sc = rsqrtf(ss * (1.f / 128.f) + REPS);

  unsigned int outw = ((unsigned int)f2b(oii * sc * w[2 * l + 1]) << 16) |
                      (unsigned int)f2b(orr * sc * w[2 * l]);
  *(unsigned int*)(p + 2 * l) = outw;
}

// ---------------- 4. causal flash attention (GQA 4:1) ----------------------
// grid: (T/64, B*16). 4 waves; wave w owns q rows [q0+16w, +16).
__global__ __launch_bounds__(256) void fattn_kernel(const unsigned short* __restrict__ qkv,
                                                    unsigned short* __restrict__ y) {
  const int qb = blockIdx.x;
  const int bh = blockIdx.y;
  const int b = bh >> 4, h = bh & 15;
  const unsigned short* base = qkv + (long)b * TT * QKVN;
  const unsigned short* Qp = base + h * 128;
  const unsigned short* Kp = base + 2048 + (h >> 2) * 128;
  const unsigned short* Vp = base + 2560 + (h >> 2) * 128;
  const int tid = threadIdx.x;
  const int l = tid & 63, w = tid >> 6;
  const int lr = l & 15, lg = l >> 4;
  const int q0 = qb * 64;
  const int qrow = q0 + w * 16;

  __shared__ unsigned short Ks[64][136];   // +8 pad -> 2-way banks on b128 reads
  __shared__ unsigned short Vt[128][72];   // V transposed, +8 pad
  __shared__ unsigned short Ps[4][16][72]; // per-wave P tile

  bf16x8 qf[4];
  {
    const unsigned short* qp = Qp + (long)(qrow + lr) * QKVN + lg * 8;
#pragma unroll
    for (int c = 0; c < 4; ++c) qf[c] = *(const bf16x8*)(qp + c * 32);
  }

  f32x4 o[8];
#pragma unroll
  for (int n = 0; n < 8; ++n) o[n] = f32x4{0.f, 0.f, 0.f, 0.f};
  float mrow[4], lsum[4];
#pragma unroll
  for (int r = 0; r < 4; ++r) { mrow[r] = -__builtin_inff(); lsum[r] = 0.f; }

  const int ntiles = qb + 1;
  for (int it = 0; it < ntiles; ++it) {
    const int kv0 = it * 64;
    __syncthreads();
    // stage K (row-major) and V (transposed)
#pragma unroll
    for (int i = 0; i < 4; ++i) {
      int idx = tid + i * 256;
      int r = idx >> 4;
      int cc = (idx & 15) * 8;
      *(u32x4*)(&Ks[r][cc]) = *(const u32x4*)(Kp + (long)(kv0 + r) * QKVN + cc);
    }
#pragma unroll
    for (int i = 0; i < 4; ++i) {
      int idx = tid + i * 256;
      int r = idx >> 4;
      int cc = (idx & 15) * 8;
      unsigned short tmp[8] __attribute__((aligned(16)));
      *(u32x4*)tmp = *(const u32x4*)(Vp + (long)(kv0 + r) * QKVN + cc);
#pragma unroll
      for (int j = 0; j < 8; ++j) Vt[cc + j][r] = tmp[j];
    }
    __syncthreads();

    // S = Q K^T  (4 col-blocks of 16)
    f32x4 sb[4];
#pragma unroll
    for (int kb = 0; kb < 4; ++kb) {
      f32x4 s = f32x4{0.f, 0.f, 0.f, 0.f};
#pragma unroll
      for (int c = 0; c < 4; ++c) {
        bf16x8 kf = *(const bf16x8*)(&Ks[kb * 16 + lr][lg * 8 + c * 32]);
        s = mfma16(qf[c], kf, s);
      }
      sb[kb] = s;
    }
    // causal mask + row max
    float rmax[4];
#pragma unroll
    for (int r = 0; r < 4; ++r) rmax[r] = -__builtin_inff();
#pragma unroll
    for (int kb = 0; kb < 4; ++kb) {
      int kcol = kv0 + kb * 16 + lr;
#pragma unroll
      for (int r = 0; r < 4; ++r) {
        int qr = qrow + lg * 4 + r;
        if (kcol > qr) sb[kb][r] = -__builtin_inff();
        rmax[r] = fmaxf(rmax[r], sb[kb][r]);
      }
    }
#pragma unroll
    for (int r = 0; r < 4; ++r)
#pragma unroll
      for (int d = 1; d < 16; d <<= 1)
        rmax[r] = fmaxf(rmax[r], __shfl_xor(rmax[r], d));

    float alpha[4];
#pragma unroll
    for (int r = 0; r < 4; ++r) {
      float mn = fmaxf(mrow[r], rmax[r] * SC2);
      alpha[r] = exp2f(mrow[r] - mn);   // exp2(-inf)=0 on first tile
      mrow[r] = mn;
    }
    float rsum[4] = {0.f, 0.f, 0.f, 0.f};
#pragma unroll
    for (int kb = 0; kb < 4; ++kb)
#pragma unroll
      for (int r = 0; r < 4; ++r) {
        float pv = exp2f(sb[kb][r] * SC2 - mrow[r]);  // masked -> exp2(-inf)=0
        rsum[r] += pv;
        Ps[w][lg * 4 + r][kb * 16 + lr] = f2b(pv);
      }
#pragma unroll
    for (int r = 0; r < 4; ++r) {
#pragma unroll
      for (int d = 1; d < 16; d <<= 1) rsum[r] += __shfl_xor(rsum[r], d);
      lsum[r] = lsum[r] * alpha[r] + rsum[r];
    }
#pragma unroll
    for (int n = 0; n < 8; ++n)
#pragma unroll
      for (int r = 0; r < 4; ++r) o[n][r] *= alpha[r];

    // wave-private LDS: ensure P writes land before A-frag reads
    asm volatile("s_waitcnt lgkmcnt(0)" ::: "memory");
    __builtin_amdgcn_sched_barrier(0);

    // O += P V
#pragma unroll
    for (int kc = 0; kc < 2; ++kc) {
      bf16x8 pf = *(const bf16x8*)(&Ps[w][lr][kc * 32 + lg * 8]);
#pragma unroll
      for (int n = 0; n < 8; ++n) {
        bf16x8 vf = *(const bf16x8*)(&Vt[n * 16 + lr][kc * 32 + lg * 8]);
        o[n] = mfma16(pf, vf, o[n]);
      }
    }
  }

  float inv[4];
#pragma unroll
  for (int r = 0; r < 4; ++r) inv[r] = 1.f / lsum[r];
  unsigned short* yp = y + (long)(b * TT + qrow) * DDIM + h * 128;
#pragma unroll
  for (int n = 0; n < 8; ++n)
#pragma unroll
    for (int r = 0; r < 4; ++r)
      yp[(long)(lg * 4 + r) * DDIM + n * 16 + lr] = f2b(o[n][r] * inv[r]);
}

// ---------------- launcher ----------------
extern "C" void kernel_launch(void* const* d_in, const int* in_sizes, int n_in,
                              void* d_out, int out_size, void* d_ws, size_t ws_size,
                              hipStream_t stream) {
  const float* x  = (const float*)d_in[0];
  const float* wq = (const float*)d_in[1];
  const float* wk = (const float*)d_in[2];
  const float* wv = (const float*)d_in[3];
  const float* wo = (const float*)d_in[4];
  const float* qw = (const float*)d_in[5];
  const float* kw = (const float*)d_in[6];
  float* out = (float*)d_out;

  // workspace carve (bf16 buffers), ~76 MB total
  unsigned short* xb   = (unsigned short*)d_ws;                 // 4096x2048
  unsigned short* wcat = xb + (size_t)MROWS * DDIM;             // 3072x2048
  unsigned short* wob  = wcat + (size_t)QKVN * DDIM;            // 2048x2048
  unsigned short* qkv  = wob + (size_t)DDIM * DDIM;             // 4096x3072
  unsigned short* yb   = qkv + (size_t)MROWS * QKVN;            // 4096x2048

  auto cvt = [&](const float* src, unsigned short* dst, long n) {
    int n4 = (int)(n / 4);
    cvt_kernel<<<(n4 + 255) / 256, 256, 0, stream>>>(src, dst, n4);
  };
  cvt(x,  xb,   (long)MROWS * DDIM);
  cvt(wq, wcat,                         (long)2048 * 2048);
  cvt(wk, wcat + (size_t)2048 * 2048,   (long)512 * 2048);
  cvt(wv, wcat + (size_t)2560 * 2048,   (long)512 * 2048);
  cvt(wo, wob,  (long)2048 * 2048);

  dim3 g1(QKVN / 128, MROWS / 128);
  gemm_bt<unsigned short><<<g1, 256, 0, stream>>>(xb, wcat, qkv, MROWS, QKVN, DDIM);

  rope_norm_kernel<<<(MROWS * 20) / 4, 256, 0, stream>>>(qkv, qw, kw);

  dim3 g2(TT / 64, 32);
  fattn_kernel<<<g2, 256, 0, stream>>>(qkv, yb);

  dim3 g3(DDIM / 128, MROWS / 128);
  gemm_bt<float><<<g3, 256, 0, stream>>>(yb, wob, out, MROWS, DDIM, DDIM);
}

// Round 2
// 491.246 us; speedup vs baseline: 1.3028x; 1.3028x over previous
//
#include <hip/hip_runtime.h>
#include <hip/hip_bf16.h>
#include <math.h>

// ---------------- types / helpers ----------------
typedef __attribute__((ext_vector_type(8))) short bf16x8;   // 8 bf16 in 4 VGPRs
typedef __attribute__((ext_vector_type(4))) float f32x4;
typedef __attribute__((ext_vector_type(4))) unsigned int u32x4;

#define DEV static __device__ __forceinline__

constexpr int TT   = 2048;      // sequence length
constexpr int DDIM = 2048;      // model dim
constexpr int QKVN = 3072;      // 2048 q + 512 k + 512 v
constexpr int MROWS = 4096;     // B*T
constexpr float RSCALE = 0.08838834764831845f;  // 1/sqrt(128)
constexpr float LOG2E  = 1.4426950408889634f;
constexpr float SC2    = RSCALE * LOG2E;
constexpr float REPS   = 1.1920928955078125e-07f;

DEV unsigned short f2b(float f) {            // f32 -> bf16 RNE
  union { float f; unsigned int u; } v; v.f = f;
  unsigned int u = v.u;
  return (unsigned short)((u + 0x7fffu + ((u >> 16) & 1u)) >> 16);
}
DEV float b2f(unsigned short h) {
  union { unsigned int u; float f; } v; v.u = ((unsigned int)h) << 16;
  return v.f;
}
DEV f32x4 mfma16(bf16x8 a, bf16x8 b, f32x4 c) {
  return __builtin_amdgcn_mfma_f32_16x16x32_bf16(a, b, c, 0, 0, 0);
}
DEV void gload_lds16(const void* g, void* l) {
  __builtin_amdgcn_global_load_lds(
      (const __attribute__((address_space(1))) unsigned int*)g,
      (__attribute__((address_space(3))) unsigned int*)l, 16, 0, 0);
}

// ---------------- 1. f32 -> bf16 convert ----------------
__global__ __launch_bounds__(256) void cvt_kernel(const float* __restrict__ in,
                                                  unsigned short* __restrict__ out,
                                                  int n4) {
  int i = blockIdx.x * 256 + threadIdx.x;
  if (i < n4) {
    float4 v = ((const float4*)in)[i];
    ushort4 o;
    o.x = f2b(v.x); o.y = f2b(v.y); o.z = f2b(v.z); o.w = f2b(v.w);
    ((ushort4*)out)[i] = o;
  }
}

// ---------------- 2/5. GEMM: C[M,N] = A[M,K] * B[N,K]^T (bf16 in, CT out) ---
template <typename CT>
__global__ __launch_bounds__(256) void gemm_bt(const unsigned short* __restrict__ A,
                                               const unsigned short* __restrict__ B,
                                               CT* __restrict__ C,
                                               int M, int N, int K) {
  __shared__ unsigned short As[128 * 32];
  __shared__ unsigned short Bs[128 * 32];
  const int tid = threadIdx.x;
  const int l = tid & 63, w = tid >> 6;
  const int wr = w >> 1, wc = w & 1;
  const long bm = (long)blockIdx.y * 128, bn = (long)blockIdx.x * 128;

  const int r0 = tid >> 2;
  const int c0 = (tid & 3) * 8;
  const unsigned short* Ag0 = A + (bm + r0) * (long)K + c0;
  const unsigned short* Ag1 = A + (bm + r0 + 64) * (long)K + c0;
  const unsigned short* Bg0 = B + (bn + r0) * (long)K + c0;
  const unsigned short* Bg1 = B + (bn + r0 + 64) * (long)K + c0;
  char* lA = (char*)As + w * 1024;
  char* lB = (char*)Bs + w * 1024;

  f32x4 acc[4][4];
#pragma unroll
  for (int m = 0; m < 4; ++m)
#pragma unroll
    for (int n = 0; n < 4; ++n) acc[m][n] = f32x4{0.f, 0.f, 0.f, 0.f};

  const int lr = l & 15;
  const int lk = (l >> 4) * 8;

  for (int k0 = 0; k0 < K; k0 += 32) {
    gload_lds16(Ag0 + k0, lA);
    gload_lds16(Ag1 + k0, lA + 4096);
    gload_lds16(Bg0 + k0, lB);
    gload_lds16(Bg1 + k0, lB + 4096);
    __syncthreads();
    bf16x8 af[4], bfr[4];
#pragma unroll
    for (int m = 0; m < 4; ++m)
      af[m] = *(const bf16x8*)(As + (wr * 64 + m * 16 + lr) * 32 + lk);
#pragma unroll
    for (int n = 0; n < 4; ++n)
      bfr[n] = *(const bf16x8*)(Bs + (wc * 64 + n * 16 + lr) * 32 + lk);
#pragma unroll
    for (int m = 0; m < 4; ++m)
#pragma unroll
      for (int n = 0; n < 4; ++n)
        acc[m][n] = mfma16(af[m], bfr[n], acc[m][n]);
    __syncthreads();
  }

#pragma unroll
  for (int m = 0; m < 4; ++m)
#pragma unroll
    for (int n = 0; n < 4; ++n)
#pragma unroll
      for (int r = 0; r < 4; ++r) {
        long row = bm + wr * 64 + m * 16 + (l >> 4) * 4 + r;
        long col = bn + wc * 64 + n * 16 + (l & 15);
        float val = acc[m][n][r];
        if constexpr (sizeof(CT) == 2)
          ((unsigned short*)C)[row * N + col] = f2b(val);
        else
          ((float*)C)[row * N + col] = val;
      }
}

// ---------------- 3. RoPE + RMSNorm (q heads 0..15, k heads 16..19) --------
__global__ __launch_bounds__(256) void rope_norm_kernel(unsigned short* __restrict__ qkv,
                                                        const float* __restrict__ qw,
                                                        const float* __restrict__ kw) {
  const int slot = blockIdx.x * 4 + (threadIdx.x >> 6);
  const int l = threadIdx.x & 63;
  const int bt = slot / 20;
  const int hs = slot - bt * 20;
  const int t = bt & (TT - 1);
  const bool isq = hs < 16;
  const int col0 = isq ? hs * 128 : 2048 + (hs - 16) * 128;
  const float* w = isq ? qw : kw;
  unsigned short* p = qkv + (long)bt * QKVN + col0;

  unsigned int pr = *(const unsigned int*)(p + 2 * l);
  float xr = b2f((unsigned short)(pr & 0xffffu));
  float xi = b2f((unsigned short)(pr >> 16));

  float ang = (float)t * exp2f(-0.207620509f * (float)l);
  float s = sinf(ang), c = cosf(ang);
  float orr = xr * c - xi * s;
  float oii = xr * s + xi * c;

  float ss = orr * orr + oii * oii;
#pragma unroll
  for (int d = 1; d < 64; d <<= 1) ss += __shfl_xor(ss, d);
  float sc = rsqrtf(ss * (1.f / 128.f) + REPS);

  unsigned int outw = ((unsigned int)f2b(oii * sc * w[2 * l + 1]) << 16) |
                      (unsigned int)f2b(orr * sc * w[2 * l]);
  *(unsigned int*)(p + 2 * l) = outw;
}

// ---------------- 4. causal flash attention (GQA 4:1), pipelined ----------
// grid (T/64, B*16); qb reversed so longest blocks dispatch first.
// K: global_load_lds into linear [64][128] with XOR swizzle applied via
//    pre-swizzled global source (read: byte ^= (row&7)<<4).
// V: global->reg (async) then swizzled transpose-scatter:
//    byte(d,kv) = d*128 + (kv*2 ^ (g(d)<<4)), g(d)=((d>>1)^(d>>3))&7
//    -> writes 2-way (free), b128 reads at bank minimum.
// One raw s_barrier per tile; prefetch flies during compute (T3/T14).
__global__ __launch_bounds__(256) void fattn_kernel(const unsigned short* __restrict__ qkv,
                                                    unsigned short* __restrict__ y) {
  const int qb = (int)gridDim.x - 1 - (int)blockIdx.x;   // longest first
  const int bh = blockIdx.y;
  const int b = bh >> 4, h = bh & 15;
  const unsigned short* base = qkv + (long)b * TT * QKVN;
  const unsigned short* Qp = base + h * 128;
  const unsigned short* Kp = base + 2048 + (h >> 2) * 128;
  const unsigned short* Vp = base + 2560 + (h >> 2) * 128;
  const int tid = threadIdx.x;
  const int l = tid & 63, w = tid >> 6;
  const int lr = l & 15, lg = l >> 4;
  const int qrow = qb * 64 + w * 16;

  __shared__ char KsB[2][16384];             // swizzled K, 64x128 bf16
  __shared__ char VtB[2][16384];             // swizzled V^T, 128x64 bf16
  __shared__ unsigned short Ps[4][16][72];   // per-wave P tile

  // ---- Q fragments (reused across all tiles) ----
  bf16x8 qf[4];
  {
    const unsigned short* qp = Qp + (long)(qrow + lr) * QKVN + lg * 8;
#pragma unroll
    for (int c = 0; c < 4; ++c) qf[c] = *(const bf16x8*)(qp + c * 32);
  }

  // ---- staging geometry (constant per thread) ----
  // K: slots s = tid + 256*i -> row = (tid>>4)+16*i, col-bytes pre-swizzled
  const int krow0 = tid >> 4;
  const int kcolb = ((tid & 15) * 16) ^ ((krow0 & 7) << 4);  // const across i
  const unsigned short* Kg = Kp + (long)krow0 * QKVN + (kcolb >> 1);
  // V: idx = tid + 256*i -> kv row = (tid>>4)+16*i, d-cols 8*(tid&15)+0..7
  const int vm = tid & 15;
  const unsigned short* Vg = Vp + (long)(tid >> 4) * QKVN + vm * 8;
  // V write offsets per j (d = 8*vm + j)
  int vwoff[8];
#pragma unroll
  for (int j = 0; j < 8; ++j) {
    int d = vm * 8 + j;
    vwoff[j] = d * 128 + (((((d >> 1) ^ (d >> 3)) & 7) << 4));
    // final byte = (d*128) + (2*kv ^ swz) ; store as base^swz pre-merged:
    // we keep vwoff = d*128 + swz and XOR-in 2*kv at write time (bits disjoint
    // under XOR semantics: byte = d*128 + ((2*kv) ^ swz) = (d*128) | x since
    // d*128 occupies bits >=7; compute via + on the XORed low part below.
  }
  const int lgk = ((lr & 7) << 4);           // K read swizzle for this lane

  f32x4 o[8];
#pragma unroll
  for (int n = 0; n < 8; ++n) o[n] = f32x4{0.f, 0.f, 0.f, 0.f};
  float mrow[4], lsum[4];
#pragma unroll
  for (int r = 0; r < 4; ++r) { mrow[r] = -__builtin_inff(); lsum[r] = 0.f; }

  const int ntiles = qb + 1;
  u32x4 vr[4];   // in-flight V tile (regs)

  // ---- prologue: stage tile 0 into buf 0 ----
  {
    char* kdst = KsB[0] + (w * 64) * 16;
#pragma unroll
    for (int i = 0; i < 4; ++i)
      gload_lds16(Kg + (long)16 * i * QKVN, kdst + i * 4096);
#pragma unroll
    for (int i = 0; i < 4; ++i)
      vr[i] = *(const u32x4*)(Vg + (long)16 * i * QKVN);
    asm volatile("s_waitcnt vmcnt(0)" ::: "memory");
    char* vt = VtB[0];
#pragma unroll
    for (int i = 0; i < 4; ++i) {
      int kv2 = 2 * ((tid >> 4) + 16 * i);
      const unsigned short* tv = (const unsigned short*)&vr[i];
#pragma unroll
      for (int j = 0; j < 8; ++j) {
        int base128 = (vm * 8 + j) * 128;
        int swz = vwoff[j] - base128;                 // = g(d)<<4
        *(unsigned short*)(vt + base128 + (kv2 ^ swz)) = tv[j];
      }
    }
    asm volatile("s_waitcnt lgkmcnt(0)" ::: "memory");
    __builtin_amdgcn_s_barrier();
  }

  int cur = 0;
  for (int it = 0; it < ntiles; ++it) {
    const int kv0 = it * 64;
    const int nxt = cur ^ 1;
    const bool pfn = (it + 1 < ntiles);

    // ---- issue next-tile loads (fly during compute) ----
    if (pfn) {
      const long adv = (long)(it + 1) * 64 * QKVN;
      char* kdst = KsB[nxt] + (w * 64) * 16;
#pragma unroll
      for (int i = 0; i < 4; ++i)
        gload_lds16(Kg + adv + (long)16 * i * QKVN, kdst + i * 4096);
#pragma unroll
      for (int i = 0; i < 4; ++i)
        vr[i] = *(const u32x4*)(Vg + adv + (long)16 * i * QKVN);
    }

    // ---- S = Q K^T (swizzled K reads), with uniform causal skip ----
    const char* KsC = KsB[cur];
    const char* VtC = VtB[cur];
    f32x4 sb[4];
#pragma unroll
    for (int kb = 0; kb < 4; ++kb) {
      if (kv0 + kb * 16 <= qrow + 15) {
        f32x4 s = f32x4{0.f, 0.f, 0.f, 0.f};
#pragma unroll
        for (int c = 0; c < 4; ++c) {
          bf16x8 kf = *(const bf16x8*)(KsC + (kb * 16 + lr) * 256 +
                                       ((16 * lg + 64 * c) ^ lgk));
          s = mfma16(qf[c], kf, s);
        }
        sb[kb] = s;
      } else {
        sb[kb] = f32x4{-__builtin_inff(), -__builtin_inff(),
                       -__builtin_inff(), -__builtin_inff()};
      }
    }

    // ---- causal mask + online softmax ----
    float rmax[4];
#pragma unroll
    for (int r = 0; r < 4; ++r) rmax[r] = -__builtin_inff();
#pragma unroll
    for (int kb = 0; kb < 4; ++kb) {
      int kcol = kv0 + kb * 16 + lr;
#pragma unroll
      for (int r = 0; r < 4; ++r) {
        int qr = qrow + lg * 4 + r;
        if (kcol > qr) sb[kb][r] = -__builtin_inff();
        rmax[r] = fmaxf(rmax[r], sb[kb][r]);
      }
    }
#pragma unroll
    for (int r = 0; r < 4; ++r)
#pragma unroll
      for (int d = 1; d < 16; d <<= 1)
        rmax[r] = fmaxf(rmax[r], __shfl_xor(rmax[r], d));

    float alpha[4];
#pragma unroll
    for (int r = 0; r < 4; ++r) {
      float mn = fmaxf(mrow[r], rmax[r] * SC2);
      alpha[r] = exp2f(mrow[r] - mn);
      mrow[r] = mn;
    }
    float rsum[4] = {0.f, 0.f, 0.f, 0.f};
#pragma unroll
    for (int kb = 0; kb < 4; ++kb)
#pragma unroll
      for (int r = 0; r < 4; ++r) {
        float pv = exp2f(sb[kb][r] * SC2 - mrow[r]);
        rsum[r] += pv;
        Ps[w][lg * 4 + r][kb * 16 + lr] = f2b(pv);
      }
#pragma unroll
    for (int r = 0; r < 4; ++r) {
#pragma unroll
      for (int d = 1; d < 16; d <<= 1) rsum[r] += __shfl_xor(rsum[r], d);
      lsum[r] = lsum[r] * alpha[r] + rsum[r];
    }
#pragma unroll
    for (int n = 0; n < 8; ++n)
#pragma unroll
      for (int r = 0; r < 4; ++r) o[n][r] *= alpha[r];

    asm volatile("s_waitcnt lgkmcnt(0)" ::: "memory");
    __builtin_amdgcn_sched_barrier(0);

    // ---- O += P V (swizzled V^T reads), uniform causal skip ----
#pragma unroll
    for (int kc = 0; kc < 2; ++kc) {
      if (kv0 + kc * 32 <= qrow + 15) {
        bf16x8 pf = *(const bf16x8*)(&Ps[w][lr][kc * 32 + lg * 8]);
#pragma unroll
        for (int n = 0; n < 8; ++n) {
          int d = n * 16 + lr;
          int swz = (((d >> 1) ^ (d >> 3)) & 7) << 4;
          bf16x8 vf = *(const bf16x8*)(VtC + d * 128 +
                                       ((kc * 64 + 16 * lg) ^ swz));
          o[n] = mfma16(pf, vf, o[n]);
        }
      }
    }

    // ---- finish next-tile stage: V writes, then one barrier ----
    if (pfn) {
      asm volatile("s_waitcnt vmcnt(0)" ::: "memory");
      char* vt = VtB[nxt];
#pragma unroll
      for (int i = 0; i < 4; ++i) {
        int kv2 = 2 * ((tid >> 4) + 16 * i);
        const unsigned short* tv = (const unsigned short*)&vr[i];
#pragma unroll
        for (int j = 0; j < 8; ++j) {
          int base128 = (vm * 8 + j) * 128;
          int swz = vwoff[j] - base128;
          *(unsigned short*)(vt + base128 + (kv2 ^ swz)) = tv[j];
        }
      }
      asm volatile("s_waitcnt lgkmcnt(0)" ::: "memory");
      __builtin_amdgcn_s_barrier();
    }
    cur = nxt;
  }

  float inv[4];
#pragma unroll
  for (int r = 0; r < 4; ++r) inv[r] = 1.f / lsum[r];
  unsigned short* yp = y + (long)(b * TT + qrow) * DDIM + h * 128;
#pragma unroll
  for (int n = 0; n < 8; ++n)
#pragma unroll
    for (int r = 0; r < 4; ++r)
      yp[(long)(lg * 4 + r) * DDIM + n * 16 + lr] = f2b(o[n][r] * inv[r]);
}

// ---------------- launcher ----------------
extern "C" void kernel_launch(void* const* d_in, const int* in_sizes, int n_in,
                              void* d_out, int out_size, void* d_ws, size_t ws_size,
                              hipStream_t stream) {
  const float* x  = (const float*)d_in[0];
  const float* wq = (const float*)d_in[1];
  const float* wk = (const float*)d_in[2];
  const float* wv = (const float*)d_in[3];
  const float* wo = (const float*)d_in[4];
  const float* qw = (const float*)d_in[5];
  const float* kw = (const float*)d_in[6];
  float* out = (float*)d_out;

  unsigned short* xb   = (unsigned short*)d_ws;                 // 4096x2048
  unsigned short* wcat = xb + (size_t)MROWS * DDIM;             // 3072x2048
  unsigned short* wob  = wcat + (size_t)QKVN * DDIM;            // 2048x2048
  unsigned short* qkv  = wob + (size_t)DDIM * DDIM;             // 4096x3072
  unsigned short* yb   = qkv + (size_t)MROWS * QKVN;            // 4096x2048

  auto cvt = [&](const float* src, unsigned short* dst, long n) {
    int n4 = (int)(n / 4);
    cvt_kernel<<<(n4 + 255) / 256, 256, 0, stream>>>(src, dst, n4);
  };
  cvt(x,  xb,   (long)MROWS * DDIM);
  cvt(wq, wcat,                         (long)2048 * 2048);
  cvt(wk, wcat + (size_t)2048 * 2048,   (long)512 * 2048);
  cvt(wv, wcat + (size_t)2560 * 2048,   (long)512 * 2048);
  cvt(wo, wob,  (long)2048 * 2048);

  dim3 g1(QKVN / 128, MROWS / 128);
  gemm_bt<unsigned short><<<g1, 256, 0, stream>>>(xb, wcat, qkv, MROWS, QKVN, DDIM);

  rope_norm_kernel<<<(MROWS * 20) / 4, 256, 0, stream>>>(qkv, qw, kw);

  dim3 g2(TT / 64, 32);
  fattn_kernel<<<g2, 256, 0, stream>>>(qkv, yb);

  dim3 g3(DDIM / 128, MROWS / 128);
  gemm_bt<float><<<g3, 256, 0, stream>>>(yb, wob, out, MROWS, DDIM, DDIM);
}

// Round 5
// 421.060 us; speedup vs baseline: 1.5200x; 1.1667x over previous
//
#include <hip/hip_runtime.h>
#include <hip/hip_bf16.h>
#include <math.h>

// ---------------- types / helpers ----------------
typedef __attribute__((ext_vector_type(8))) short bf16x8;   // 8 bf16 in 4 VGPRs
typedef __attribute__((ext_vector_type(4))) float f32x4;
typedef __attribute__((ext_vector_type(4))) unsigned int u32x4;
typedef __attribute__((ext_vector_type(2))) unsigned int u32x2;

#define DEV static __device__ __forceinline__

constexpr int TT   = 2048;      // sequence length
constexpr int DDIM = 2048;      // model dim
constexpr int QKVN = 3072;      // 2048 q + 512 k + 512 v
constexpr int MROWS = 4096;     // B*T
constexpr float RSCALE = 0.08838834764831845f;  // 1/sqrt(128)
constexpr float LOG2E  = 1.4426950408889634f;
constexpr float SC2    = RSCALE * LOG2E;
constexpr float REPS   = 1.1920928955078125e-07f;

DEV unsigned short f2b(float f) {            // f32 -> bf16 RNE
  union { float f; unsigned int u; } v; v.f = f;
  unsigned int u = v.u;
  return (unsigned short)((u + 0x7fffu + ((u >> 16) & 1u)) >> 16);
}
DEV float b2f(unsigned short h) {
  union { unsigned int u; float f; } v; v.u = ((unsigned int)h) << 16;
  return v.f;
}
DEV f32x4 mfma16(bf16x8 a, bf16x8 b, f32x4 c) {
  return __builtin_amdgcn_mfma_f32_16x16x32_bf16(a, b, c, 0, 0, 0);
}
DEV void gload_lds16(const void* g, void* l) {
  __builtin_amdgcn_global_load_lds(
      (const __attribute__((address_space(1))) unsigned int*)g,
      (__attribute__((address_space(3))) unsigned int*)l, 16, 0, 0);
}
DEV unsigned int cvtpk(float lo, float hi) {  // packed f32->bf16 pair (1 instr)
  unsigned int r;
  asm("v_cvt_pk_bf16_f32 %0, %1, %2" : "=v"(r) : "v"(lo), "v"(hi));
  return r;
}
union PB { u32x4 u; bf16x8 b; };

// ---------------- 1. f32 -> bf16 convert ----------------
__global__ __launch_bounds__(256) void cvt_kernel(const float* __restrict__ in,
                                                  unsigned short* __restrict__ out,
                                                  int n4) {
  int i = blockIdx.x * 256 + threadIdx.x;
  if (i < n4) {
    float4 v = ((const float4*)in)[i];
    ushort4 o;
    o.x = f2b(v.x); o.y = f2b(v.y); o.z = f2b(v.z); o.w = f2b(v.w);
    ((ushort4*)out)[i] = o;
  }
}

// ---------------- 2/5. GEMM: C[M,N] = A[M,K] * B[N,K]^T (bf16 in, CT out) ---
// 128x128 tile, BK=32, 4 waves; 2-phase pipeline (T3 minimum recipe):
// stage(next) issued BEFORE ds_read+MFMA(cur); one __syncthreads per K-step.
template <typename CT>
__global__ __launch_bounds__(256) void gemm_bt(const unsigned short* __restrict__ A,
                                               const unsigned short* __restrict__ B,
                                               CT* __restrict__ C,
                                               int M, int N, int K) {
  __shared__ unsigned short As[2][128 * 32];
  __shared__ unsigned short Bs[2][128 * 32];
  const int tid = threadIdx.x;
  const int l = tid & 63, w = tid >> 6;
  const int wr = w >> 1, wc = w & 1;
  const long bm = (long)blockIdx.y * 128, bn = (long)blockIdx.x * 128;

  const int r0 = tid >> 2;
  const int c0 = (tid & 3) * 8;
  const unsigned short* Ag0 = A + (bm + r0) * (long)K + c0;
  const unsigned short* Ag1 = A + (bm + r0 + 64) * (long)K + c0;
  const unsigned short* Bg0 = B + (bn + r0) * (long)K + c0;
  const unsigned short* Bg1 = B + (bn + r0 + 64) * (long)K + c0;

  f32x4 acc[4][4];
#pragma unroll
  for (int m = 0; m < 4; ++m)
#pragma unroll
    for (int n = 0; n < 4; ++n) acc[m][n] = f32x4{0.f, 0.f, 0.f, 0.f};

  const int lr = l & 15;
  const int lk = (l >> 4) * 8;

  // prologue: stage k0=0 into buf 0
  {
    char* lA = (char*)(As[0]) + w * 1024;
    char* lB = (char*)(Bs[0]) + w * 1024;
    gload_lds16(Ag0, lA);
    gload_lds16(Ag1, lA + 4096);
    gload_lds16(Bg0, lB);
    gload_lds16(Bg1, lB + 4096);
  }
  __syncthreads();

  int cur = 0;
  for (int k0 = 0; k0 < K; k0 += 32) {
    if (k0 + 32 < K) {           // issue next-tile stage; flies under MFMA
      char* lA = (char*)(As[cur ^ 1]) + w * 1024;
      char* lB = (char*)(Bs[cur ^ 1]) + w * 1024;
      gload_lds16(Ag0 + k0 + 32, lA);
      gload_lds16(Ag1 + k0 + 32, lA + 4096);
      gload_lds16(Bg0 + k0 + 32, lB);
      gload_lds16(Bg1 + k0 + 32, lB + 4096);
    }
    const unsigned short* Asc = As[cur];
    const unsigned short* Bsc = Bs[cur];
    bf16x8 af[4], bfr[4];
#pragma unroll
    for (int m = 0; m < 4; ++m)
      af[m] = *(const bf16x8*)(Asc + (wr * 64 + m * 16 + lr) * 32 + lk);
#pragma unroll
    for (int n = 0; n < 4; ++n)
      bfr[n] = *(const bf16x8*)(Bsc + (wc * 64 + n * 16 + lr) * 32 + lk);
#pragma unroll
    for (int m = 0; m < 4; ++m)
#pragma unroll
      for (int n = 0; n < 4; ++n)
        acc[m][n] = mfma16(af[m], bfr[n], acc[m][n]);
    __syncthreads();             // drains stage (vmcnt0) + guards buffers
    cur ^= 1;
  }

#pragma unroll
  for (int m = 0; m < 4; ++m)
#pragma unroll
    for (int n = 0; n < 4; ++n)
#pragma unroll
      for (int r = 0; r < 4; ++r) {
        long row = bm + wr * 64 + m * 16 + (l >> 4) * 4 + r;
        long col = bn + wc * 64 + n * 16 + (l & 15);
        float val = acc[m][n][r];
        if constexpr (sizeof(CT) == 2)
          ((unsigned short*)C)[row * N + col] = f2b(val);
        else
          ((float*)C)[row * N + col] = val;
      }
}

// ---------------- 3. RoPE + RMSNorm (q heads 0..15, k heads 16..19) --------
__global__ __launch_bounds__(256) void rope_norm_kernel(unsigned short* __restrict__ qkv,
                                                        const float* __restrict__ qw,
                                                        const float* __restrict__ kw) {
  const int slot = blockIdx.x * 4 + (threadIdx.x >> 6);
  const int l = threadIdx.x & 63;
  const int bt = slot / 20;
  const int hs = slot - bt * 20;
  const int t = bt & (TT - 1);
  const bool isq = hs < 16;
  const int col0 = isq ? hs * 128 : 2048 + (hs - 16) * 128;
  const float* w = isq ? qw : kw;
  unsigned short* p = qkv + (long)bt * QKVN + col0;

  unsigned int pr = *(const unsigned int*)(p + 2 * l);
  float xr = b2f((unsigned short)(pr & 0xffffu));
  float xi = b2f((unsigned short)(pr >> 16));

  float ang = (float)t * exp2f(-0.207620509f * (float)l);
  float s = sinf(ang), c = cosf(ang);
  float orr = xr * c - xi * s;
  float oii = xr * s + xi * c;

  float ss = orr * orr + oii * oii;
#pragma unroll
  for (int d = 1; d < 64; d <<= 1) ss += __shfl_xor(ss, d);
  float sc = rsqrtf(ss * (1.f / 128.f) + REPS);

  unsigned int outw = ((unsigned int)f2b(oii * sc * w[2 * l + 1]) << 16) |
                      (unsigned int)f2b(orr * sc * w[2 * l]);
  *(unsigned int*)(p + 2 * l) = outw;
}

// ---------------- 4. causal flash attention (GQA 4:1) ----------------------
// grid (16, B*16): block bx does qb = 31-bx then qb = bx (33 tiles, balanced).
// Swapped QK^T: sT = mfma(K,Q) -> lane holds S[q=qrow+lr][k=kv0+16kb+4lg+r]:
// row softmax is in-register (+2 shfl_xor). PV uses a sigma-permuted k-order
// (k = 16(2c+(j>>2)) + 4lg + (j&3) for mfma slot kk=8lg+j) applied to BOTH
// operands: A-frag = lane's own cvt_pk'd P (no cross-lane, no LDS), B-frag =
// two ds_read_b64 from swizzled Vt per (c,n). Defer-max (THR=8), setprio.
__global__ __launch_bounds__(256) void fattn_kernel(const unsigned short* __restrict__ qkv,
                                                    unsigned short* __restrict__ y) {
  const int bx = blockIdx.x;
  const int bh = blockIdx.y;
  const int b = bh >> 4, h = bh & 15;
  const unsigned short* base = qkv + (long)b * TT * QKVN;
  const unsigned short* Qp = base + h * 128;
  const unsigned short* Kp = base + 2048 + (h >> 2) * 128;
  const unsigned short* Vp = base + 2560 + (h >> 2) * 128;
  const int tid = threadIdx.x;
  const int l = tid & 63, w = tid >> 6;
  const int lr = l & 15, lg = l >> 4;

  __shared__ char KsB[2][16384];             // swizzled K, 64x128 bf16
  __shared__ char VtB[2][16384];             // swizzled V^T, 128x64 bf16

  // staging geometry (constant per thread)
  const int krow0 = tid >> 4;
  const int kcolb = ((tid & 15) * 16) ^ ((krow0 & 7) << 4);
  const unsigned short* Kg = Kp + (long)krow0 * QKVN + (kcolb >> 1);
  const int vm = tid & 15;
  const unsigned short* Vg = Vp + (long)(tid >> 4) * QKVN + vm * 8;
  const int lgk = ((lr & 7) << 4);           // K read swizzle

  for (int seg = 0; seg < 2; ++seg) {
    const int qb = seg ? bx : (31 - bx);
    const int qrow = qb * 64 + w * 16;
    const int ntiles = qb + 1;

    bf16x8 qf[4];
    {
      const unsigned short* qp = Qp + (long)(qrow + lr) * QKVN + lg * 8;
#pragma unroll
      for (int c = 0; c < 4; ++c) qf[c] = *(const bf16x8*)(qp + c * 32);
    }

    f32x4 o[8];
#pragma unroll
    for (int n = 0; n < 8; ++n) o[n] = f32x4{0.f, 0.f, 0.f, 0.f};
    float m = -__builtin_inff(), lsum = 0.f;

    __syncthreads();   // protect LDS from previous segment's readers

    u32x4 vr[4];
    // ---- prologue: stage tile 0 into buf 0 ----
    {
      char* kdst = KsB[0] + (w * 64) * 16;
#pragma unroll
      for (int i = 0; i < 4; ++i)
        gload_lds16(Kg + (long)16 * i * QKVN, kdst + i * 4096);
#pragma unroll
      for (int i = 0; i < 4; ++i)
        vr[i] = *(const u32x4*)(Vg + (long)16 * i * QKVN);
      asm volatile("s_waitcnt vmcnt(0)" ::: "memory");
      char* vt = VtB[0];
#pragma unroll
      for (int i = 0; i < 4; ++i) {
        int kv2 = 2 * ((tid >> 4) + 16 * i);
        const unsigned short* tv = (const unsigned short*)&vr[i];
#pragma unroll
        for (int j = 0; j < 8; ++j) {
          int d = vm * 8 + j;
          int swz = (((d >> 1) ^ (d >> 3)) & 7) << 4;
          *(unsigned short*)(vt + d * 128 + (kv2 ^ swz)) = tv[j];
        }
      }
      asm volatile("s_waitcnt lgkmcnt(0)" ::: "memory");
      __builtin_amdgcn_sched_barrier(0);
      __builtin_amdgcn_s_barrier();
    }

    int cur = 0;
    for (int it = 0; it < ntiles; ++it) {
      const int kv0 = it * 64;
      const int nxt = cur ^ 1;
      const bool pfn = (it + 1 < ntiles);

      // ---- issue next-tile loads (fly during compute) ----
      if (pfn) {
        const long adv = (long)(it + 1) * 64 * QKVN;
        char* kdst = KsB[nxt] + (w * 64) * 16;
#pragma unroll
        for (int i = 0; i < 4; ++i)
          gload_lds16(Kg + adv + (long)16 * i * QKVN, kdst + i * 4096);
#pragma unroll
        for (int i = 0; i < 4; ++i)
          vr[i] = *(const u32x4*)(Vg + adv + (long)16 * i * QKVN);
      }

      const char* KsC = KsB[cur];
      const char* VtC = VtB[cur];

      // ---- S^T = K Q^T : lane -> S[qrow+lr][kv0+16kb+4lg+r] ----
      f32x4 sT[4];
      __builtin_amdgcn_s_setprio(1);
#pragma unroll
      for (int kb = 0; kb < 4; ++kb) {
        if (kv0 + kb * 16 <= qrow + 15) {
          f32x4 s = f32x4{0.f, 0.f, 0.f, 0.f};
#pragma unroll
          for (int c = 0; c < 4; ++c) {
            bf16x8 kf = *(const bf16x8*)(KsC + (kb * 16 + lr) * 256 +
                                         ((16 * lg + 64 * c) ^ lgk));
            s = mfma16(kf, qf[c], s);   // swapped operands
          }
          sT[kb] = s;
        } else {
          sT[kb] = f32x4{-__builtin_inff(), -__builtin_inff(),
                         -__builtin_inff(), -__builtin_inff()};
        }
      }
      __builtin_amdgcn_s_setprio(0);

      // ---- causal mask; needed iff kv0+63 > qrow  <=>  kv0+48 >= qrow ----
      if (kv0 + 48 >= qrow) {
#pragma unroll
        for (int kb = 0; kb < 4; ++kb)
#pragma unroll
          for (int r = 0; r < 4; ++r) {
            int ks = kv0 + kb * 16 + 4 * lg + r;
            sT[kb][r] = (ks > qrow + lr) ? -__builtin_inff() : sT[kb][r];
          }
      }

      // ---- in-register online softmax (row = lane's lr) ----
      float pmax = -__builtin_inff();
#pragma unroll
      for (int kb = 0; kb < 4; ++kb)
#pragma unroll
        for (int r = 0; r < 4; ++r) pmax = fmaxf(pmax, sT[kb][r]);
      pmax = fmaxf(pmax, __shfl_xor(pmax, 16));
      pmax = fmaxf(pmax, __shfl_xor(pmax, 32));
      pmax *= SC2;

      if (!__all(pmax <= m + 8.f)) {     // defer-max: rescale rarely
        float mn = fmaxf(m, pmax);
        float al = exp2f(m - mn);
        m = mn;
        lsum *= al;
        float ao[4];
#pragma unroll
        for (int r = 0; r < 4; ++r) ao[r] = __shfl(al, 20 * lg + r);
#pragma unroll
        for (int n = 0; n < 8; ++n)
#pragma unroll
          for (int r = 0; r < 4; ++r) o[n][r] *= ao[r];
      }

      float rs = 0.f;
      unsigned int pk[4][2];
#pragma unroll
      for (int kb = 0; kb < 4; ++kb) {
        float p0 = exp2f(sT[kb][0] * SC2 - m);
        float p1 = exp2f(sT[kb][1] * SC2 - m);
        float p2 = exp2f(sT[kb][2] * SC2 - m);
        float p3 = exp2f(sT[kb][3] * SC2 - m);
        rs += (p0 + p1) + (p2 + p3);
        pk[kb][0] = cvtpk(p0, p1);
        pk[kb][1] = cvtpk(p2, p3);
      }
      rs += __shfl_xor(rs, 16);
      rs += __shfl_xor(rs, 32);
      lsum += rs;

      // ---- O += P V (sigma-permuted k-order on both operands) ----
      __builtin_amdgcn_s_setprio(1);
#pragma unroll
      for (int c = 0; c < 2; ++c) {
        if (kv0 + c * 32 <= qrow + 15) {
          PB pb;
          pb.u = u32x4{pk[2 * c][0], pk[2 * c][1], pk[2 * c + 1][0], pk[2 * c + 1][1]};
#pragma unroll
          for (int n = 0; n < 8; ++n) {
            int d = n * 16 + lr;
            int gsw = (((d >> 1) ^ (d >> 3)) & 7) << 4;
            const char* vb = VtC + d * 128;
            u32x2 vlo = *(const u32x2*)(vb + ((64 * c + 8 * lg) ^ gsw));
            u32x2 vhi = *(const u32x2*)(vb + ((64 * c + 32 + 8 * lg) ^ gsw));
            PB vv; vv.u = u32x4{vlo[0], vlo[1], vhi[0], vhi[1]};
            o[n] = mfma16(pb.b, vv.b, o[n]);
          }
        }
      }
      __builtin_amdgcn_s_setprio(0);

      // ---- finish next-tile stage: V writes, then one barrier ----
      if (pfn) {
        asm volatile("s_waitcnt vmcnt(0)" ::: "memory");
        char* vt = VtB[nxt];
#pragma unroll
        for (int i = 0; i < 4; ++i) {
          int kv2 = 2 * ((tid >> 4) + 16 * i);
          const unsigned short* tv = (const unsigned short*)&vr[i];
#pragma unroll
          for (int j = 0; j < 8; ++j) {
            int d = vm * 8 + j;
            int swz = (((d >> 1) ^ (d >> 3)) & 7) << 4;
            *(unsigned short*)(vt + d * 128 + (kv2 ^ swz)) = tv[j];
          }
        }
        asm volatile("s_waitcnt lgkmcnt(0)" ::: "memory");
        __builtin_amdgcn_sched_barrier(0);
        __builtin_amdgcn_s_barrier();
      }
      cur = nxt;
    }

    // ---- epilogue ----
    float inv = 1.f / lsum;
    float io[4];
#pragma unroll
    for (int r = 0; r < 4; ++r) io[r] = __shfl(inv, 20 * lg + r);
    unsigned short* yp = y + (long)(b * TT + qrow) * DDIM + h * 128;
#pragma unroll
    for (int n = 0; n < 8; ++n)
#pragma unroll
      for (int r = 0; r < 4; ++r)
        yp[(long)(lg * 4 + r) * DDIM + n * 16 + lr] = f2b(o[n][r] * io[r]);
  }
}

// ---------------- launcher ----------------
extern "C" void kernel_launch(void* const* d_in, const int* in_sizes, int n_in,
                              void* d_out, int out_size, void* d_ws, size_t ws_size,
                              hipStream_t stream) {
  const float* x  = (const float*)d_in[0];
  const float* wq = (const float*)d_in[1];
  const float* wk = (const float*)d_in[2];
  const float* wv = (const float*)d_in[3];
  const float* wo = (const float*)d_in[4];
  const float* qw = (const float*)d_in[5];
  const float* kw = (const float*)d_in[6];
  float* out = (float*)d_out;

  unsigned short* xb   = (unsigned short*)d_ws;                 // 4096x2048
  unsigned short* wcat = xb + (size_t)MROWS * DDIM;             // 3072x2048
  unsigned short* wob  = wcat + (size_t)QKVN * DDIM;            // 2048x2048
  unsigned short* qkv  = wob + (size_t)DDIM * DDIM;             // 4096x3072
  unsigned short* yb   = qkv + (size_t)MROWS * QKVN;            // 4096x2048

  auto cvt = [&](const float* src, unsigned short* dst, long n) {
    int n4 = (int)(n / 4);
    cvt_kernel<<<(n4 + 255) / 256, 256, 0, stream>>>(src, dst, n4);
  };
  cvt(x,  xb,   (long)MROWS * DDIM);
  cvt(wq, wcat,                         (long)2048 * 2048);
  cvt(wk, wcat + (size_t)2048 * 2048,   (long)512 * 2048);
  cvt(wv, wcat + (size_t)2560 * 2048,   (long)512 * 2048);
  cvt(wo, wob,  (long)2048 * 2048);

  dim3 g1(QKVN / 128, MROWS / 128);
  gemm_bt<unsigned short><<<g1, 256, 0, stream>>>(xb, wcat, qkv, MROWS, QKVN, DDIM);

  rope_norm_kernel<<<(MROWS * 20) / 4, 256, 0, stream>>>(qkv, qw, kw);

  dim3 g2(16, 32);
  fattn_kernel<<<g2, 256, 0, stream>>>(qkv, yb);

  dim3 g3(DDIM / 128, MROWS / 128);
  gemm_bt<float><<<g3, 256, 0, stream>>>(yb, wob, out, MROWS, DDIM, DDIM);
}